// Round 2
// baseline (135.775 us; speedup 1.0000x reference)
//
#include <hip/hip_runtime.h>

typedef unsigned short u16;
typedef __attribute__((ext_vector_type(2))) float f2;

// ---------- packed complex helpers (v_pk_fma_f32: 2 f32 FMA / inst) ----------
// c += a*b (complex):  c.x += ax*bx - ay*by ; c.y += ax*by + ay*bx
__device__ __forceinline__ void cmad_pk(f2& c, f2 a, f2 b){
  asm("v_pk_fma_f32 %0, %1, %2, %0 op_sel:[0,0,0] op_sel_hi:[0,1,1]\n\t"
      "v_pk_fma_f32 %0, %1, %2, %0 op_sel:[1,1,0] op_sel_hi:[1,0,1] neg_lo:[1,0,0]"
      : "+v"(c) : "v"(a), "v"(b));
}
// d = a*b (complex)
__device__ __forceinline__ f2 cmul_pk(f2 a, f2 b){
  f2 d;
  asm("v_pk_mul_f32 %0, %1, %2 op_sel:[0,0] op_sel_hi:[0,1]\n\t"
      "v_pk_fma_f32 %0, %1, %2, %0 op_sel:[1,1,0] op_sel_hi:[1,0,1] neg_lo:[1,0,0]"
      : "=&v"(d) : "v"(a), "v"(b));
  return d;
}
__device__ __forceinline__ f2 pk_mul(f2 a, f2 b){
  f2 d; asm("v_pk_mul_f32 %0, %1, %2" : "=v"(d) : "v"(a), "v"(b)); return d;
}
__device__ __forceinline__ f2 pk_fma(f2 a, f2 b, f2 c){
  f2 d; asm("v_pk_fma_f32 %0, %1, %2, %3" : "=v"(d) : "v"(a), "v"(b), "v"(c)); return d;
}

// ---------- scalar complex (setup only) ----------
__device__ __forceinline__ float2 cmul(float2 a, float2 b){
  return make_float2(a.x*b.x - a.y*b.y, a.x*b.y + a.y*b.x);
}
__device__ __forceinline__ float2 cmad(float2 acc, float2 a, float2 b){
  acc.x += a.x*b.x - a.y*b.y; acc.y += a.x*b.y + a.y*b.x; return acc;
}
struct M2 { float2 m[4]; };
struct M4 { float2 m[16]; };
__device__ M2 mul2(const M2 A, const M2 B){
  M2 C;
  #pragma unroll
  for (int r=0;r<2;r++)
    #pragma unroll
    for (int c=0;c<2;c++){
      float2 v = cmul(A.m[2*r+0], B.m[0+c]);
      v = cmad(v, A.m[2*r+1], B.m[2+c]);
      C.m[2*r+c] = v;
    }
  return C;
}
__device__ M4 mul4(const M4 A, const M4 B){
  M4 C;
  #pragma unroll
  for (int r=0;r<4;r++)
    #pragma unroll
    for (int c=0;c<4;c++){
      float2 v = cmul(A.m[4*r+0], B.m[0+c]);
      v = cmad(v, A.m[4*r+1], B.m[4+c]);
      v = cmad(v, A.m[4*r+2], B.m[8+c]);
      v = cmad(v, A.m[4*r+3], B.m[12+c]);
      C.m[4*r+c] = v;
    }
  return C;
}
__device__ M4 kron(const M2 A, const M2 B){
  M4 M;
  #pragma unroll
  for (int ia=0;ia<2;ia++)
    #pragma unroll
    for (int ib=0;ib<2;ib++)
      #pragma unroll
      for (int ja=0;ja<2;ja++)
        #pragma unroll
        for (int jb=0;jb<2;jb++)
          M.m[(2*ia+ib)*4 + (2*ja+jb)] = cmul(A.m[2*ia+ja], B.m[2*ib+jb]);
  return M;
}
__device__ M2 mRX(float t){ float c=cosf(0.5f*t), s=sinf(0.5f*t); M2 M;
  M.m[0]=make_float2(c,0.f); M.m[1]=make_float2(0.f,-s);
  M.m[2]=make_float2(0.f,-s); M.m[3]=make_float2(c,0.f); return M; }
__device__ M2 mRY(float t){ float c=cosf(0.5f*t), s=sinf(0.5f*t); M2 M;
  M.m[0]=make_float2(c,0.f); M.m[1]=make_float2(-s,0.f);
  M.m[2]=make_float2(s,0.f); M.m[3]=make_float2(c,0.f); return M; }
__device__ M2 mRZ(float t){ float c=cosf(0.5f*t), s=sinf(0.5f*t); M2 M;
  M.m[0]=make_float2(c,-s); M.m[1]=make_float2(0.f,0.f);
  M.m[2]=make_float2(0.f,0.f); M.m[3]=make_float2(c,s); return M; }
__device__ M2 mH(){ const float r=0.70710678118654752f; M2 M;
  M.m[0]=make_float2(r,0.f); M.m[1]=make_float2(r,0.f);
  M.m[2]=make_float2(r,0.f); M.m[3]=make_float2(-r,0.f); return M; }
__device__ M4 vqc_gate(const M2 A1, const M2 B1, const M2 A2, const M2 B2){
  M4 M = kron(A1,B1);
  #pragma unroll
  for (int c=0;c<4;c++){ M.m[12+c].x=-M.m[12+c].x; M.m[12+c].y=-M.m[12+c].y; } // CZ
  M4 T = mul4(kron(A2,B2), M);
  #pragma unroll
  for (int c=0;c<4;c++){ float2 tmp=T.m[4+c]; T.m[4+c]=T.m[12+c]; T.m[12+c]=tmp; } // CNOT(b->a)
  return T;
}

// ---------- setup: fused gates (column-major), perm table, combined bias ----------
__global__ void qm_setup(const float* __restrict__ params, const float* __restrict__ w_fc,
                         const float* __restrict__ b_in, const float* __restrict__ b_fc,
                         float* __restrict__ wsf, u16* __restrict__ ptab){
  int t = threadIdx.x;
  if (t < 5){
    int i = t;
    const float* p1 = params + 10 + i*12;
    const float* p2 = params + 70 + i*12;
    float ea = params[2*i], eb = params[2*i+1];
    M2 A1 = mul2(mRZ(p1[4]), mul2(mRY(p1[2]), mul2(mRX(p1[0]), mul2(mRY(ea), mH()))));
    M2 B1 = mul2(mRX(p1[5]), mul2(mRZ(p1[3]), mul2(mRY(p1[1]), mul2(mRY(eb), mH()))));
    M2 A2 = mul2(mRX(p1[10]), mul2(mRY(p1[8]), mRZ(p1[6])));
    M2 B2 = mul2(mRY(p1[11]), mul2(mRZ(p1[9]), mRX(p1[7])));
    M4 G1 = vqc_gate(A1,B1,A2,B2);
    M2 A1b = mul2(mRZ(p2[4]), mul2(mRY(p2[2]), mRX(p2[0])));
    M2 B1b = mul2(mRX(p2[5]), mul2(mRZ(p2[3]), mRY(p2[1])));
    M2 A2b = mul2(mRX(p2[10]), mul2(mRY(p2[8]), mRZ(p2[6])));
    M2 B2b = mul2(mRY(p2[11]), mul2(mRZ(p2[9]), mRX(p2[7])));
    M4 G = mul4(vqc_gate(A1b,B1b,A2b,B2b), G1);
    float2* dst = (float2*)wsf + i*16;
    #pragma unroll
    for (int r=0;r<4;r++)
      #pragma unroll
      for (int c=0;c<4;c++) dst[c*4+r]=G.m[r*4+c];   // column-major
  } else if (t < 10){
    int i = t-5;
    const float* sa = params + 130 + (2*i)*3;
    const float* sb = params + 130 + (2*i+1)*3;
    M2 Ra = mul2(mRZ(sa[2]), mul2(mRY(sa[1]), mRZ(sa[0])));
    M2 Rb = mul2(mRZ(sb[2]), mul2(mRY(sb[1]), mRZ(sb[0])));
    M4 R = kron(Ra, Rb);
    float2* dst = (float2*)wsf + 80 + i*16;
    #pragma unroll
    for (int r=0;r<4;r++)
      #pragma unroll
      for (int c=0;c<4;c++) dst[c*4+r]=R.m[r*4+c];   // column-major
  } else if (t < 20){
    int c = t-10;                                    // cbias = b_fc + w_fc @ b_in
    float s = b_fc[c];
    #pragma unroll
    for (int q=0;q<10;q++) s += w_fc[c*10+q]*b_in[q];
    wsf[320+c] = s;
  }
  for (int s=t; s<1024; s+=blockDim.x){
    int bb[10];
    #pragma unroll
    for (int w=0;w<10;w++) bb[w] = (s>>(9-w))&1;
    #pragma unroll
    for (int i=0;i<10;i++) bb[(i+1)%10] ^= bb[i];
    int sp=0;
    #pragma unroll
    for (int w=0;w<10;w++) sp |= bb[w]<<(9-w);
    ptab[s]=(u16)sp;
  }
}

// ---------- one 4x4 gate pass (column-streamed, packed-complex) ----------
template<int PB, bool SCATTER>
__device__ __forceinline__ void gate_pass(f2* psi, const f2* gm, ushort4 pidx, int t){
  constexpr int ST = 1<<PB;
  f2 c0,c1,c2,c3;
  int base;
  if constexpr (PB==0){
    base = 4*t;
    const float4* p4 = (const float4*)psi;
    float4 u = p4[2*t], w = p4[2*t+1];                 // contiguous b128: conflict-free
    f2 a0={u.x,u.y}, a1={u.z,u.w}, a2={w.x,w.y}, a3={w.z,w.w};
    const float4* g4 = (const float4*)gm;
    float4 ga, gb; f2 g0,g1,g2,g3;
    ga=g4[0]; gb=g4[1]; g0={ga.x,ga.y}; g1={ga.z,ga.w}; g2={gb.x,gb.y}; g3={gb.z,gb.w};
    c0=cmul_pk(g0,a0); c1=cmul_pk(g1,a0); c2=cmul_pk(g2,a0); c3=cmul_pk(g3,a0);
    ga=g4[2]; gb=g4[3]; g0={ga.x,ga.y}; g1={ga.z,ga.w}; g2={gb.x,gb.y}; g3={gb.z,gb.w};
    cmad_pk(c0,g0,a1); cmad_pk(c1,g1,a1); cmad_pk(c2,g2,a1); cmad_pk(c3,g3,a1);
    ga=g4[4]; gb=g4[5]; g0={ga.x,ga.y}; g1={ga.z,ga.w}; g2={gb.x,gb.y}; g3={gb.z,gb.w};
    cmad_pk(c0,g0,a2); cmad_pk(c1,g1,a2); cmad_pk(c2,g2,a2); cmad_pk(c3,g3,a2);
    ga=g4[6]; gb=g4[7]; g0={ga.x,ga.y}; g1={ga.z,ga.w}; g2={gb.x,gb.y}; g3={gb.z,gb.w};
    cmad_pk(c0,g0,a3); cmad_pk(c1,g1,a3); cmad_pk(c2,g2,a3); cmad_pk(c3,g3,a3);
  } else if constexpr (PB==2){
    // lane-rotated column order: conflict-free strided reads (matvec is order-indep)
    constexpr int M = ST-1;
    base = ((t & ~M) << 2) | (t & M);
    int r0 = (t>>2)&3;
    #pragma unroll
    for (int i=0;i<4;i++){
      int cc = (r0+i)&3;
      f2 a = psi[base + (cc<<PB)];
      const float4* g4 = (const float4*)(gm + (cc<<2));
      float4 ga=g4[0], gb=g4[1];
      f2 g0={ga.x,ga.y}, g1={ga.z,ga.w}, g2={gb.x,gb.y}, g3={gb.z,gb.w};
      if (i==0){ c0=cmul_pk(g0,a); c1=cmul_pk(g1,a); c2=cmul_pk(g2,a); c3=cmul_pk(g3,a); }
      else     { cmad_pk(c0,g0,a); cmad_pk(c1,g1,a); cmad_pk(c2,g2,a); cmad_pk(c3,g3,a); }
    }
  } else {
    constexpr int M = ST-1;
    base = ((t & ~M) << 2) | (t & M);
    f2 a0=psi[base], a1=psi[base+ST], a2=psi[base+2*ST], a3=psi[base+3*ST];
    const float4* g4 = (const float4*)gm;
    float4 ga, gb; f2 g0,g1,g2,g3;
    ga=g4[0]; gb=g4[1]; g0={ga.x,ga.y}; g1={ga.z,ga.w}; g2={gb.x,gb.y}; g3={gb.z,gb.w};
    c0=cmul_pk(g0,a0); c1=cmul_pk(g1,a0); c2=cmul_pk(g2,a0); c3=cmul_pk(g3,a0);
    ga=g4[2]; gb=g4[3]; g0={ga.x,ga.y}; g1={ga.z,ga.w}; g2={gb.x,gb.y}; g3={gb.z,gb.w};
    cmad_pk(c0,g0,a1); cmad_pk(c1,g1,a1); cmad_pk(c2,g2,a1); cmad_pk(c3,g3,a1);
    ga=g4[4]; gb=g4[5]; g0={ga.x,ga.y}; g1={ga.z,ga.w}; g2={gb.x,gb.y}; g3={gb.z,gb.w};
    cmad_pk(c0,g0,a2); cmad_pk(c1,g1,a2); cmad_pk(c2,g2,a2); cmad_pk(c3,g3,a2);
    ga=g4[6]; gb=g4[7]; g0={ga.x,ga.y}; g1={ga.z,ga.w}; g2={gb.x,gb.y}; g3={gb.z,gb.w};
    cmad_pk(c0,g0,a3); cmad_pk(c1,g1,a3); cmad_pk(c2,g2,a3); cmad_pk(c3,g3,a3);
  }
  if constexpr (SCATTER){
    psi[pidx.x]=c0; psi[pidx.y]=c1; psi[pidx.z]=c2; psi[pidx.w]=c3;   // ring perm folded in
  } else if constexpr (PB==0){
    float4* p4 = (float4*)psi;
    p4[2*t]   = make_float4(c0.x,c0.y,c1.x,c1.y);
    p4[2*t+1] = make_float4(c2.x,c2.y,c3.x,c3.y);
  } else {
    psi[base]=c0; psi[base+ST]=c1; psi[base+2*ST]=c2; psi[base+3*ST]=c3;
  }
  __syncthreads();
}

// ---------- main: one block = one sample ----------
__global__ __launch_bounds__(256) void qm_sim(
    const float* __restrict__ x, const float* __restrict__ w_in,
    const float* __restrict__ w_fc, const float* __restrict__ wsf,
    const u16* __restrict__ ptab, float* __restrict__ out)
{
  __shared__ __align__(16) f2 psi[1024];
  __shared__ __align__(16) f2 gmat[160];
  __shared__ float redN[4];
  __shared__ float redX[4][10];
  __shared__ float redM[4][9];
  __shared__ float Mv[10];
  __shared__ float XV[10];
  const int t = threadIdx.x;
  const int b = blockIdx.x;
  const int lane = t & 63, wid = t >> 6;

  ushort4 pidx = ((const ushort4*)ptab)[t];            // perm for states 4t..4t+3

  // x row + partial dots
  float4 xv = ((const float4*)x)[(size_t)b*256 + t];
  f2 xa = {xv.x, xv.y}, xb = {xv.z, xv.w};
  f2 nn = pk_fma(xa, xa, pk_mul(xb, xb));
  float n2 = nn.x + nn.y;
  float xp[10];
  #pragma unroll
  for (int q=0;q<10;q++){
    float4 wv = ((const float4*)w_in)[q*256 + t];
    f2 wa = {wv.x, wv.y}, wb = {wv.z, wv.w};
    f2 pr = pk_fma(xa, wa, pk_mul(xb, wb));
    xp[q] = pr.x + pr.y;
  }
  #pragma unroll
  for (int o=32;o;o>>=1) n2 += __shfl_xor(n2, o);
  if (lane==0) redN[wid] = n2;
  if (t < 80) ((float4*)gmat)[t] = ((const float4*)wsf)[t];   // stage gates in LDS
  __syncthreads();
  float rn = rsqrtf(redN[0]+redN[1]+redN[2]+redN[3]);
  {
    float4* p4 = (float4*)psi;
    p4[2*t]   = make_float4(xv.x*rn, 0.f, xv.y*rn, 0.f);
    p4[2*t+1] = make_float4(xv.z*rn, 0.f, xv.w*rn, 0.f);
  }
  // reduce xp while psi-write settles (fills barrier bubble), then free the regs
  #pragma unroll
  for (int q=0;q<10;q++){
    float v = xp[q];
    #pragma unroll
    for (int o=32;o;o>>=1) v += __shfl_xor(v, o);
    xp[q] = v;
  }
  if (lane==0){
    #pragma unroll
    for (int q=0;q<10;q++) redX[wid][q] = xp[q];
  }
  __syncthreads();

  // 5 fused VQC-pair gates (H+emb+layer1+layer2); last one scatters ring-1 perm
  gate_pass<8,false>(psi, gmat +  0, pidx, t);
  gate_pass<6,false>(psi, gmat + 16, pidx, t);
  gate_pass<4,false>(psi, gmat + 32, pidx, t);
  gate_pass<2,false>(psi, gmat + 48, pidx, t);
  gate_pass<0,true >(psi, gmat + 64, pidx, t);
  // 5 fused rot-pair gates; last one scatters ring-2 perm
  gate_pass<8,false>(psi, gmat + 80, pidx, t);
  gate_pass<6,false>(psi, gmat + 96, pidx, t);
  gate_pass<4,false>(psi, gmat +112, pidx, t);
  gate_pass<2,false>(psi, gmat +128, pidx, t);
  gate_pass<0,true >(psi, gmat +144, pidx, t);

  // epilogue: hierarchical signed reduction -> all 10 bit-marginals
  // state s = 256c + t : bit9=c>>1, bit8=c&1, bits7:6=wid, bits5:0=lane
  float p0,p1,p2,p3;
  { f2 a=psi[t      ]; p0 = a.x*a.x + a.y*a.y; }
  { f2 a=psi[t+256  ]; p1 = a.x*a.x + a.y*a.y; }
  { f2 a=psi[t+512  ]; p2 = a.x*a.x + a.y*a.y; }
  { f2 a=psi[t+768  ]; p3 = a.x*a.x + a.y*a.y; }
  float t01=p0+p1, t23=p2+p3, u01=p0-p1, u23=p2-p3;
  float S  = t01+t23;
  float D9 = t01-t23;
  float D8 = u01+u23;
  float D0,D1,D2,D3,D4,D5;
  { const int k=1;  float Sp=__shfl_xor(S,k); float d=S-Sp; D0=(lane&k)?-d:d; S+=Sp;
    D9+=__shfl_xor(D9,k); D8+=__shfl_xor(D8,k); }
  { const int k=2;  float Sp=__shfl_xor(S,k); float d=S-Sp; D1=(lane&k)?-d:d; S+=Sp;
    D9+=__shfl_xor(D9,k); D8+=__shfl_xor(D8,k); D0+=__shfl_xor(D0,k); }
  { const int k=4;  float Sp=__shfl_xor(S,k); float d=S-Sp; D2=(lane&k)?-d:d; S+=Sp;
    D9+=__shfl_xor(D9,k); D8+=__shfl_xor(D8,k); D0+=__shfl_xor(D0,k); D1+=__shfl_xor(D1,k); }
  { const int k=8;  float Sp=__shfl_xor(S,k); float d=S-Sp; D3=(lane&k)?-d:d; S+=Sp;
    D9+=__shfl_xor(D9,k); D8+=__shfl_xor(D8,k); D0+=__shfl_xor(D0,k); D1+=__shfl_xor(D1,k);
    D2+=__shfl_xor(D2,k); }
  { const int k=16; float Sp=__shfl_xor(S,k); float d=S-Sp; D4=(lane&k)?-d:d; S+=Sp;
    D9+=__shfl_xor(D9,k); D8+=__shfl_xor(D8,k); D0+=__shfl_xor(D0,k); D1+=__shfl_xor(D1,k);
    D2+=__shfl_xor(D2,k); D3+=__shfl_xor(D3,k); }
  { const int k=32; float Sp=__shfl_xor(S,k); float d=S-Sp; D5=(lane&k)?-d:d; S+=Sp;
    D9+=__shfl_xor(D9,k); D8+=__shfl_xor(D8,k); D0+=__shfl_xor(D0,k); D1+=__shfl_xor(D1,k);
    D2+=__shfl_xor(D2,k); D3+=__shfl_xor(D3,k); D4+=__shfl_xor(D4,k); }
  if (lane==0){
    redM[wid][0]=S;  redM[wid][1]=D9; redM[wid][2]=D8;
    redM[wid][3]=D0; redM[wid][4]=D1; redM[wid][5]=D2;
    redM[wid][6]=D3; redM[wid][7]=D4; redM[wid][8]=D5;
  }
  __syncthreads();
  if (t < 9){
    float r0=redM[0][t], r1=redM[1][t], r2=redM[2][t], r3=redM[3][t];
    if (t==0){ Mv[7]=(r0+r1)-(r2+r3); Mv[6]=(r0-r1)+(r2-r3); }
    else if (t==1) Mv[9]=r0+r1+r2+r3;
    else if (t==2) Mv[8]=r0+r1+r2+r3;
    else           Mv[t-3]=r0+r1+r2+r3;
  } else if (t>=16 && t<26){
    int q=t-16; XV[q]=redX[0][q]+redX[1][q]+redX[2][q]+redX[3][q];
  }
  __syncthreads();
  if (t < 10){
    float o = wsf[320+t];                      // b_fc + w_fc@b_in
    #pragma unroll
    for (int q=0;q<10;q++) o += w_fc[t*10+q]*(Mv[9-q] + XV[q]);
    out[(size_t)b*10 + t] = o;
  }
}

extern "C" void kernel_launch(void* const* d_in, const int* in_sizes, int n_in,
                              void* d_out, int out_size, void* d_ws, size_t ws_size,
                              hipStream_t stream) {
  const float* x      = (const float*)d_in[0];
  const float* params = (const float*)d_in[1];
  const float* w_in   = (const float*)d_in[2];
  const float* b_in   = (const float*)d_in[3];
  const float* w_fc   = (const float*)d_in[4];
  const float* b_fc   = (const float*)d_in[5];
  float* out = (float*)d_out;

  float* wsf  = (float*)d_ws;                      // 320 f gate mats + 10 f cbias
  u16*   ptab = (u16*)((char*)d_ws + 1344);        // 1024 u16 perm table (8B aligned)

  int batch = in_sizes[0] >> 10;                   // 8192

  qm_setup<<<dim3(1), dim3(256), 0, stream>>>(params, w_fc, b_in, b_fc, wsf, ptab);
  qm_sim<<<dim3(batch), dim3(256), 0, stream>>>(x, w_in, w_fc, wsf, ptab, out);
}

// Round 3
// 116.758 us; speedup vs baseline: 1.1629x; 1.1629x over previous
//
#include <hip/hip_runtime.h>

typedef unsigned short u16;
typedef __attribute__((ext_vector_type(2))) float f2;

// bank-conflict swizzle: XOR bits [7:4] into [3:0]; involution, bijective on [0,1024)
__device__ __forceinline__ int SW(int i){ return i ^ ((i>>4)&15); }

// ---------- packed complex helpers (v_pk_fma_f32: 2 f32 FMA / inst) ----------
__device__ __forceinline__ void cmad_pk(f2& c, f2 a, f2 b){
  asm("v_pk_fma_f32 %0, %1, %2, %0 op_sel:[0,0,0] op_sel_hi:[0,1,1]\n\t"
      "v_pk_fma_f32 %0, %1, %2, %0 op_sel:[1,1,0] op_sel_hi:[1,0,1] neg_lo:[1,0,0]"
      : "+v"(c) : "v"(a), "v"(b));
}
__device__ __forceinline__ f2 cmul_pk(f2 a, f2 b){
  f2 d;
  asm("v_pk_mul_f32 %0, %1, %2 op_sel:[0,0] op_sel_hi:[0,1]\n\t"
      "v_pk_fma_f32 %0, %1, %2, %0 op_sel:[1,1,0] op_sel_hi:[1,0,1] neg_lo:[1,0,0]"
      : "=&v"(d) : "v"(a), "v"(b));
  return d;
}
__device__ __forceinline__ f2 pk_mul(f2 a, f2 b){
  f2 d; asm("v_pk_mul_f32 %0, %1, %2" : "=v"(d) : "v"(a), "v"(b)); return d;
}
__device__ __forceinline__ f2 pk_fma(f2 a, f2 b, f2 c){
  f2 d; asm("v_pk_fma_f32 %0, %1, %2, %3" : "=v"(d) : "v"(a), "v"(b), "v"(c)); return d;
}

// ---------- scalar complex (setup only) ----------
__device__ __forceinline__ float2 cmul(float2 a, float2 b){
  return make_float2(a.x*b.x - a.y*b.y, a.x*b.y + a.y*b.x);
}
__device__ __forceinline__ float2 cmad(float2 acc, float2 a, float2 b){
  acc.x += a.x*b.x - a.y*b.y; acc.y += a.x*b.y + a.y*b.x; return acc;
}
struct M2 { float2 m[4]; };
struct M4 { float2 m[16]; };
__device__ M2 mul2(const M2 A, const M2 B){
  M2 C;
  #pragma unroll
  for (int r=0;r<2;r++)
    #pragma unroll
    for (int c=0;c<2;c++){
      float2 v = cmul(A.m[2*r+0], B.m[0+c]);
      v = cmad(v, A.m[2*r+1], B.m[2+c]);
      C.m[2*r+c] = v;
    }
  return C;
}
__device__ M4 mul4(const M4 A, const M4 B){
  M4 C;
  #pragma unroll
  for (int r=0;r<4;r++)
    #pragma unroll
    for (int c=0;c<4;c++){
      float2 v = cmul(A.m[4*r+0], B.m[0+c]);
      v = cmad(v, A.m[4*r+1], B.m[4+c]);
      v = cmad(v, A.m[4*r+2], B.m[8+c]);
      v = cmad(v, A.m[4*r+3], B.m[12+c]);
      C.m[4*r+c] = v;
    }
  return C;
}
__device__ M4 kron(const M2 A, const M2 B){
  M4 M;
  #pragma unroll
  for (int ia=0;ia<2;ia++)
    #pragma unroll
    for (int ib=0;ib<2;ib++)
      #pragma unroll
      for (int ja=0;ja<2;ja++)
        #pragma unroll
        for (int jb=0;jb<2;jb++)
          M.m[(2*ia+ib)*4 + (2*ja+jb)] = cmul(A.m[2*ia+ja], B.m[2*ib+jb]);
  return M;
}
__device__ M2 mRX(float t){ float c=cosf(0.5f*t), s=sinf(0.5f*t); M2 M;
  M.m[0]=make_float2(c,0.f); M.m[1]=make_float2(0.f,-s);
  M.m[2]=make_float2(0.f,-s); M.m[3]=make_float2(c,0.f); return M; }
__device__ M2 mRY(float t){ float c=cosf(0.5f*t), s=sinf(0.5f*t); M2 M;
  M.m[0]=make_float2(c,0.f); M.m[1]=make_float2(-s,0.f);
  M.m[2]=make_float2(s,0.f); M.m[3]=make_float2(c,0.f); return M; }
__device__ M2 mRZ(float t){ float c=cosf(0.5f*t), s=sinf(0.5f*t); M2 M;
  M.m[0]=make_float2(c,-s); M.m[1]=make_float2(0.f,0.f);
  M.m[2]=make_float2(0.f,0.f); M.m[3]=make_float2(c,s); return M; }
__device__ M2 mH(){ const float r=0.70710678118654752f; M2 M;
  M.m[0]=make_float2(r,0.f); M.m[1]=make_float2(r,0.f);
  M.m[2]=make_float2(r,0.f); M.m[3]=make_float2(-r,0.f); return M; }
__device__ M4 vqc_gate(const M2 A1, const M2 B1, const M2 A2, const M2 B2){
  M4 M = kron(A1,B1);
  #pragma unroll
  for (int c=0;c<4;c++){ M.m[12+c].x=-M.m[12+c].x; M.m[12+c].y=-M.m[12+c].y; } // CZ
  M4 T = mul4(kron(A2,B2), M);
  #pragma unroll
  for (int c=0;c<4;c++){ float2 tmp=T.m[4+c]; T.m[4+c]=T.m[12+c]; T.m[12+c]=tmp; } // CNOT(b->a)
  return T;
}

// ---------- setup: fused gates (column-major), swizzled perm table, bias ----------
__global__ void qm_setup(const float* __restrict__ params, const float* __restrict__ w_fc,
                         const float* __restrict__ b_in, const float* __restrict__ b_fc,
                         float* __restrict__ wsf, u16* __restrict__ ptab){
  int t = threadIdx.x;
  if (t < 5){
    int i = t;
    const float* p1 = params + 10 + i*12;
    const float* p2 = params + 70 + i*12;
    float ea = params[2*i], eb = params[2*i+1];
    M2 A1 = mul2(mRZ(p1[4]), mul2(mRY(p1[2]), mul2(mRX(p1[0]), mul2(mRY(ea), mH()))));
    M2 B1 = mul2(mRX(p1[5]), mul2(mRZ(p1[3]), mul2(mRY(p1[1]), mul2(mRY(eb), mH()))));
    M2 A2 = mul2(mRX(p1[10]), mul2(mRY(p1[8]), mRZ(p1[6])));
    M2 B2 = mul2(mRY(p1[11]), mul2(mRZ(p1[9]), mRX(p1[7])));
    M4 G1 = vqc_gate(A1,B1,A2,B2);
    M2 A1b = mul2(mRZ(p2[4]), mul2(mRY(p2[2]), mRX(p2[0])));
    M2 B1b = mul2(mRX(p2[5]), mul2(mRZ(p2[3]), mRY(p2[1])));
    M2 A2b = mul2(mRX(p2[10]), mul2(mRY(p2[8]), mRZ(p2[6])));
    M2 B2b = mul2(mRY(p2[11]), mul2(mRZ(p2[9]), mRX(p2[7])));
    M4 G = mul4(vqc_gate(A1b,B1b,A2b,B2b), G1);
    float2* dst = (float2*)wsf + i*16;
    #pragma unroll
    for (int r=0;r<4;r++)
      #pragma unroll
      for (int c=0;c<4;c++) dst[c*4+r]=G.m[r*4+c];   // column-major
  } else if (t < 10){
    int i = t-5;
    const float* sa = params + 130 + (2*i)*3;
    const float* sb = params + 130 + (2*i+1)*3;
    M2 Ra = mul2(mRZ(sa[2]), mul2(mRY(sa[1]), mRZ(sa[0])));
    M2 Rb = mul2(mRZ(sb[2]), mul2(mRY(sb[1]), mRZ(sb[0])));
    M4 R = kron(Ra, Rb);
    float2* dst = (float2*)wsf + 80 + i*16;
    #pragma unroll
    for (int r=0;r<4;r++)
      #pragma unroll
      for (int c=0;c<4;c++) dst[c*4+r]=R.m[r*4+c];   // column-major
  } else if (t < 20){
    int c = t-10;                                    // cbias = b_fc + w_fc @ b_in
    float s = b_fc[c];
    #pragma unroll
    for (int q=0;q<10;q++) s += w_fc[c*10+q]*b_in[q];
    wsf[320+c] = s;
  }
  // ptab[s] = SW(P(s)); P = CNOT(i,(i+1)%10) for i=0..9 in order; wire w <-> bit 9-w
  for (int s=t; s<1024; s+=blockDim.x){
    int bb[10];
    #pragma unroll
    for (int w=0;w<10;w++) bb[w] = (s>>(9-w))&1;
    #pragma unroll
    for (int i=0;i<10;i++) bb[(i+1)%10] ^= bb[i];
    int sp=0;
    #pragma unroll
    for (int w=0;w<10;w++) sp |= bb[w]<<(9-w);
    ptab[s]=(u16)SW(sp);
  }
}

// ---------- gate core: c = G(col-major, global/uniform) * a ----------
__device__ __forceinline__ void gate_mv(const float4* __restrict__ g4,
                                        f2 a0, f2 a1, f2 a2, f2 a3,
                                        f2& c0, f2& c1, f2& c2, f2& c3){
  float4 ga, gb; f2 g0,g1,g2,g3;
  ga=g4[0]; gb=g4[1]; g0={ga.x,ga.y}; g1={ga.z,ga.w}; g2={gb.x,gb.y}; g3={gb.z,gb.w};
  c0=cmul_pk(g0,a0); c1=cmul_pk(g1,a0); c2=cmul_pk(g2,a0); c3=cmul_pk(g3,a0);
  ga=g4[2]; gb=g4[3]; g0={ga.x,ga.y}; g1={ga.z,ga.w}; g2={gb.x,gb.y}; g3={gb.z,gb.w};
  cmad_pk(c0,g0,a1); cmad_pk(c1,g1,a1); cmad_pk(c2,g2,a1); cmad_pk(c3,g3,a1);
  ga=g4[4]; gb=g4[5]; g0={ga.x,ga.y}; g1={ga.z,ga.w}; g2={gb.x,gb.y}; g3={gb.z,gb.w};
  cmad_pk(c0,g0,a2); cmad_pk(c1,g1,a2); cmad_pk(c2,g2,a2); cmad_pk(c3,g3,a2);
  ga=g4[6]; gb=g4[7]; g0={ga.x,ga.y}; g1={ga.z,ga.w}; g2={gb.x,gb.y}; g3={gb.z,gb.w};
  cmad_pk(c0,g0,a3); cmad_pk(c1,g1,a3); cmad_pk(c2,g2,a3); cmad_pk(c3,g3,a3);
}

// normal pass: thread owns its 4-state group; swizzled LDS addressing
template<int PB, int GOFF>
__device__ __forceinline__ void gate_pass(f2* psi, const float4* __restrict__ gg, int t){
  constexpr int ST = 1<<PB;
  constexpr int M  = ST-1;
  const int base = ((t & ~M) << 2) | (t & M);
  const int i0=SW(base), i1=SW(base+ST), i2=SW(base+2*ST), i3=SW(base+3*ST);
  f2 a0=psi[i0], a1=psi[i1], a2=psi[i2], a3=psi[i3];
  f2 c0,c1,c2,c3;
  gate_mv(gg+GOFF, a0,a1,a2,a3, c0,c1,c2,c3);
  psi[i0]=c0; psi[i1]=c1; psi[i2]=c2; psi[i3]=c3;
  __syncthreads();
}

// PB=0 pass + ring permutation scatter (barrier between read and cross-thread write)
template<int GOFF>
__device__ __forceinline__ void gate_pass_scatter(f2* psi, const float4* __restrict__ gg,
                                                  ushort4 pidx, int t){
  const int base = 4*t;
  const int i0=SW(base), i1=SW(base+1), i2=SW(base+2), i3=SW(base+3);
  f2 a0=psi[i0], a1=psi[i1], a2=psi[i2], a3=psi[i3];
  f2 c0,c1,c2,c3;
  gate_mv(gg+GOFF, a0,a1,a2,a3, c0,c1,c2,c3);
  __syncthreads();                                   // all reads done before scatter
  psi[pidx.x]=c0; psi[pidx.y]=c1; psi[pidx.z]=c2; psi[pidx.w]=c3;
  __syncthreads();
}

// final PB=0 pass: scatter scalar probabilities (ring-2 perm folded into targets)
template<int GOFF>
__device__ __forceinline__ void gate_pass_final(f2* psi, float* pf,
                                                const float4* __restrict__ gg,
                                                ushort4 pidx, int t){
  const int base = 4*t;
  const int i0=SW(base), i1=SW(base+1), i2=SW(base+2), i3=SW(base+3);
  f2 a0=psi[i0], a1=psi[i1], a2=psi[i2], a3=psi[i3];
  f2 c0,c1,c2,c3;
  gate_mv(gg+GOFF, a0,a1,a2,a3, c0,c1,c2,c3);
  __syncthreads();                                   // all reads done before overwrite
  pf[pidx.x]=c0.x*c0.x+c0.y*c0.y;
  pf[pidx.y]=c1.x*c1.x+c1.y*c1.y;
  pf[pidx.z]=c2.x*c2.x+c2.y*c2.y;
  pf[pidx.w]=c3.x*c3.x+c3.y*c3.y;
  __syncthreads();
}

// ---------- main: one block = one sample ----------
__global__ __launch_bounds__(256) void qm_sim(
    const float* __restrict__ x, const float* __restrict__ w_in,
    const float* __restrict__ w_fc, const float* __restrict__ wsf,
    const u16* __restrict__ ptab, float* __restrict__ out)
{
  __shared__ __align__(16) f2 psi[1024];
  __shared__ float redN[4];
  __shared__ float redX[4][10];
  __shared__ float redM[4][9];
  __shared__ float Mv[10];
  __shared__ float XV[10];
  const int t = threadIdx.x;
  const int b = blockIdx.x;
  const int lane = t & 63, wid = t >> 6;
  const float4* gg = (const float4*)wsf;             // gates: global, uniform (scalar loads)
  float* pf = (float*)psi;                           // float view for prob scatter

  ushort4 pidx = ((const ushort4*)ptab)[t];          // SW(P(4t+k))

  // x row + partial dots
  float4 xv = ((const float4*)x)[(size_t)b*256 + t];
  f2 xa = {xv.x, xv.y}, xb = {xv.z, xv.w};
  f2 nn = pk_fma(xa, xa, pk_mul(xb, xb));
  float n2 = nn.x + nn.y;
  float xp[10];
  #pragma unroll
  for (int q=0;q<10;q++){
    float4 wv = ((const float4*)w_in)[q*256 + t];
    f2 wa = {wv.x, wv.y}, wb = {wv.z, wv.w};
    f2 pr = pk_fma(xa, wa, pk_mul(xb, wb));
    xp[q] = pr.x + pr.y;
  }
  #pragma unroll
  for (int o=32;o;o>>=1) n2 += __shfl_xor(n2, o);
  if (lane==0) redN[wid] = n2;
  __syncthreads();
  float rn = rsqrtf(redN[0]+redN[1]+redN[2]+redN[3]);
  psi[SW(4*t+0)] = f2{xv.x*rn, 0.f};
  psi[SW(4*t+1)] = f2{xv.y*rn, 0.f};
  psi[SW(4*t+2)] = f2{xv.z*rn, 0.f};
  psi[SW(4*t+3)] = f2{xv.w*rn, 0.f};
  // reduce xp while psi writes settle
  #pragma unroll
  for (int q=0;q<10;q++){
    float v = xp[q];
    #pragma unroll
    for (int o=32;o;o>>=1) v += __shfl_xor(v, o);
    xp[q] = v;
  }
  if (lane==0){
    #pragma unroll
    for (int q=0;q<10;q++) redX[wid][q] = xp[q];
  }
  __syncthreads();

  // 5 fused VQC-pair gates; 5th scatters ring-1 perm
  gate_pass<8, 0>(psi, gg, t);
  gate_pass<6, 8>(psi, gg, t);
  gate_pass<4,16>(psi, gg, t);
  gate_pass<2,24>(psi, gg, t);
  gate_pass_scatter<32>(psi, gg, pidx, t);
  // 5 fused rot-pair gates; 10th scatters ring-2 perm as probabilities
  gate_pass<8,40>(psi, gg, t);
  gate_pass<6,48>(psi, gg, t);
  gate_pass<4,56>(psi, gg, t);
  gate_pass<2,64>(psi, gg, t);
  gate_pass_final<72>(psi, pf, gg, pidx, t);

  // epilogue: hierarchical signed reduction -> all 10 bit-marginals
  // logical state s = 256k + t : bit9=k>>1, bit8=k&1, bits7:6=wid, bits5:0=lane
  float p0 = pf[SW(t)], p1 = pf[SW(t+256)], p2 = pf[SW(t+512)], p3 = pf[SW(t+768)];
  float t01=p0+p1, t23=p2+p3, u01=p0-p1, u23=p2-p3;
  float S  = t01+t23;
  float D9 = t01-t23;
  float D8 = u01+u23;
  float D0,D1,D2,D3,D4,D5;
  { const int k=1;  float Sp=__shfl_xor(S,k); float d=S-Sp; D0=(lane&k)?-d:d; S+=Sp;
    D9+=__shfl_xor(D9,k); D8+=__shfl_xor(D8,k); }
  { const int k=2;  float Sp=__shfl_xor(S,k); float d=S-Sp; D1=(lane&k)?-d:d; S+=Sp;
    D9+=__shfl_xor(D9,k); D8+=__shfl_xor(D8,k); D0+=__shfl_xor(D0,k); }
  { const int k=4;  float Sp=__shfl_xor(S,k); float d=S-Sp; D2=(lane&k)?-d:d; S+=Sp;
    D9+=__shfl_xor(D9,k); D8+=__shfl_xor(D8,k); D0+=__shfl_xor(D0,k); D1+=__shfl_xor(D1,k); }
  { const int k=8;  float Sp=__shfl_xor(S,k); float d=S-Sp; D3=(lane&k)?-d:d; S+=Sp;
    D9+=__shfl_xor(D9,k); D8+=__shfl_xor(D8,k); D0+=__shfl_xor(D0,k); D1+=__shfl_xor(D1,k);
    D2+=__shfl_xor(D2,k); }
  { const int k=16; float Sp=__shfl_xor(S,k); float d=S-Sp; D4=(lane&k)?-d:d; S+=Sp;
    D9+=__shfl_xor(D9,k); D8+=__shfl_xor(D8,k); D0+=__shfl_xor(D0,k); D1+=__shfl_xor(D1,k);
    D2+=__shfl_xor(D2,k); D3+=__shfl_xor(D3,k); }
  { const int k=32; float Sp=__shfl_xor(S,k); float d=S-Sp; D5=(lane&k)?-d:d; S+=Sp;
    D9+=__shfl_xor(D9,k); D8+=__shfl_xor(D8,k); D0+=__shfl_xor(D0,k); D1+=__shfl_xor(D1,k);
    D2+=__shfl_xor(D2,k); D3+=__shfl_xor(D3,k); D4+=__shfl_xor(D4,k); }
  if (lane==0){
    redM[wid][0]=S;  redM[wid][1]=D9; redM[wid][2]=D8;
    redM[wid][3]=D0; redM[wid][4]=D1; redM[wid][5]=D2;
    redM[wid][6]=D3; redM[wid][7]=D4; redM[wid][8]=D5;
  }
  __syncthreads();
  if (t < 9){
    float r0=redM[0][t], r1=redM[1][t], r2=redM[2][t], r3=redM[3][t];
    if (t==0){ Mv[7]=(r0+r1)-(r2+r3); Mv[6]=(r0-r1)+(r2-r3); }
    else if (t==1) Mv[9]=r0+r1+r2+r3;
    else if (t==2) Mv[8]=r0+r1+r2+r3;
    else           Mv[t-3]=r0+r1+r2+r3;
  } else if (t>=16 && t<26){
    int q=t-16; XV[q]=redX[0][q]+redX[1][q]+redX[2][q]+redX[3][q];
  }
  __syncthreads();
  if (t < 10){
    float o = wsf[320+t];                      // b_fc + w_fc@b_in
    #pragma unroll
    for (int q=0;q<10;q++) o += w_fc[t*10+q]*(Mv[9-q] + XV[q]);
    out[(size_t)b*10 + t] = o;
  }
}

extern "C" void kernel_launch(void* const* d_in, const int* in_sizes, int n_in,
                              void* d_out, int out_size, void* d_ws, size_t ws_size,
                              hipStream_t stream) {
  const float* x      = (const float*)d_in[0];
  const float* params = (const float*)d_in[1];
  const float* w_in   = (const float*)d_in[2];
  const float* b_in   = (const float*)d_in[3];
  const float* w_fc   = (const float*)d_in[4];
  const float* b_fc   = (const float*)d_in[5];
  float* out = (float*)d_out;

  float* wsf  = (float*)d_ws;                      // 320 f gate mats + 10 f cbias
  u16*   ptab = (u16*)((char*)d_ws + 1344);        // 1024 u16 swizzled perm table

  int batch = in_sizes[0] >> 10;                   // 8192

  qm_setup<<<dim3(1), dim3(256), 0, stream>>>(params, w_fc, b_in, b_fc, wsf, ptab);
  qm_sim<<<dim3(batch), dim3(256), 0, stream>>>(x, w_in, w_fc, wsf, ptab, out);
}

// Round 4
// 82.968 us; speedup vs baseline: 1.6365x; 1.4073x over previous
//
#include <hip/hip_runtime.h>

typedef __attribute__((ext_vector_type(2))) float f2;

#define WAIT_LDS asm volatile("s_waitcnt lgkmcnt(0)" ::: "memory")

__device__ __forceinline__ f2 mk(float a, float b){ f2 r; r.x=a; r.y=b; return r; }

// ---------- packed complex, gate operand in SGPR pair ----------
__device__ __forceinline__ void cmadS(f2& c, f2 g, f2 b){
  asm("v_pk_fma_f32 %0, %1, %2, %0 op_sel:[0,0,0] op_sel_hi:[0,1,1]\n\t"
      "v_pk_fma_f32 %0, %1, %2, %0 op_sel:[1,1,0] op_sel_hi:[1,0,1] neg_lo:[1,0,0]"
      : "+v"(c) : "s"(g), "v"(b));
}
__device__ __forceinline__ f2 cmulS(f2 g, f2 b){
  f2 d;
  asm("v_pk_mul_f32 %0, %1, %2 op_sel:[0,0] op_sel_hi:[0,1]\n\t"
      "v_pk_fma_f32 %0, %1, %2, %0 op_sel:[1,1,0] op_sel_hi:[1,0,1] neg_lo:[1,0,0]"
      : "=&v"(d) : "s"(g), "v"(b));
  return d;
}
// c_r = sum_c G[c*4+r] * a_c  (G column-major, uniform -> SGPR)
__device__ __forceinline__ void quadS(const f2* __restrict__ G, f2& a0, f2& a1, f2& a2, f2& a3){
  f2 c0,c1,c2,c3;
  c0=cmulS(G[0],a0);  c1=cmulS(G[1],a0);  c2=cmulS(G[2],a0);  c3=cmulS(G[3],a0);
  cmadS(c0,G[4],a1);  cmadS(c1,G[5],a1);  cmadS(c2,G[6],a1);  cmadS(c3,G[7],a1);
  cmadS(c0,G[8],a2);  cmadS(c1,G[9],a2);  cmadS(c2,G[10],a2); cmadS(c3,G[11],a2);
  cmadS(c0,G[12],a3); cmadS(c1,G[13],a3); cmadS(c2,G[14],a3); cmadS(c3,G[15],a3);
  a0=c0; a1=c1; a2=c2; a3=c3;
}

// ---------- scalar complex (setup only) ----------
__device__ __forceinline__ float2 cmul(float2 a, float2 b){
  return make_float2(a.x*b.x - a.y*b.y, a.x*b.y + a.y*b.x);
}
__device__ __forceinline__ float2 cmad(float2 acc, float2 a, float2 b){
  acc.x += a.x*b.x - a.y*b.y; acc.y += a.x*b.y + a.y*b.x; return acc;
}
struct M2 { float2 m[4]; };
struct M4 { float2 m[16]; };
__device__ M2 mul2(const M2 A, const M2 B){
  M2 C;
  #pragma unroll
  for (int r=0;r<2;r++)
    #pragma unroll
    for (int c=0;c<2;c++){
      float2 v = cmul(A.m[2*r+0], B.m[0+c]);
      v = cmad(v, A.m[2*r+1], B.m[2+c]);
      C.m[2*r+c] = v;
    }
  return C;
}
__device__ M4 mul4(const M4 A, const M4 B){
  M4 C;
  #pragma unroll
  for (int r=0;r<4;r++)
    #pragma unroll
    for (int c=0;c<4;c++){
      float2 v = cmul(A.m[4*r+0], B.m[0+c]);
      v = cmad(v, A.m[4*r+1], B.m[4+c]);
      v = cmad(v, A.m[4*r+2], B.m[8+c]);
      v = cmad(v, A.m[4*r+3], B.m[12+c]);
      C.m[4*r+c] = v;
    }
  return C;
}
__device__ M4 kron(const M2 A, const M2 B){
  M4 M;
  #pragma unroll
  for (int ia=0;ia<2;ia++)
    #pragma unroll
    for (int ib=0;ib<2;ib++)
      #pragma unroll
      for (int ja=0;ja<2;ja++)
        #pragma unroll
        for (int jb=0;jb<2;jb++)
          M.m[(2*ia+ib)*4 + (2*ja+jb)] = cmul(A.m[2*ia+ja], B.m[2*ib+jb]);
  return M;
}
__device__ M2 mRX(float t){ float c=cosf(0.5f*t), s=sinf(0.5f*t); M2 M;
  M.m[0]=make_float2(c,0.f); M.m[1]=make_float2(0.f,-s);
  M.m[2]=make_float2(0.f,-s); M.m[3]=make_float2(c,0.f); return M; }
__device__ M2 mRY(float t){ float c=cosf(0.5f*t), s=sinf(0.5f*t); M2 M;
  M.m[0]=make_float2(c,0.f); M.m[1]=make_float2(-s,0.f);
  M.m[2]=make_float2(s,0.f); M.m[3]=make_float2(c,0.f); return M; }
__device__ M2 mRZ(float t){ float c=cosf(0.5f*t), s=sinf(0.5f*t); M2 M;
  M.m[0]=make_float2(c,-s); M.m[1]=make_float2(0.f,0.f);
  M.m[2]=make_float2(0.f,0.f); M.m[3]=make_float2(c,s); return M; }
__device__ M2 mH(){ const float r=0.70710678118654752f; M2 M;
  M.m[0]=make_float2(r,0.f); M.m[1]=make_float2(r,0.f);
  M.m[2]=make_float2(r,0.f); M.m[3]=make_float2(-r,0.f); return M; }
__device__ M4 vqc_gate(const M2 A1, const M2 B1, const M2 A2, const M2 B2){
  M4 M = kron(A1,B1);
  #pragma unroll
  for (int c=0;c<4;c++){ M.m[12+c].x=-M.m[12+c].x; M.m[12+c].y=-M.m[12+c].y; } // CZ
  M4 T = mul4(kron(A2,B2), M);
  #pragma unroll
  for (int c=0;c<4;c++){ float2 tmp=T.m[4+c]; T.m[4+c]=T.m[12+c]; T.m[12+c]=tmp; } // CNOT(b->a)
  return T;
}

// ---------- setup: fused gates (column-major) + combined bias ----------
__global__ void qm_setup(const float* __restrict__ params, const float* __restrict__ w_fc,
                         const float* __restrict__ b_in, const float* __restrict__ b_fc,
                         float* __restrict__ wsf){
  int t = threadIdx.x;
  if (t < 5){
    int i = t;
    const float* p1 = params + 10 + i*12;
    const float* p2 = params + 70 + i*12;
    float ea = params[2*i], eb = params[2*i+1];
    M2 A1 = mul2(mRZ(p1[4]), mul2(mRY(p1[2]), mul2(mRX(p1[0]), mul2(mRY(ea), mH()))));
    M2 B1 = mul2(mRX(p1[5]), mul2(mRZ(p1[3]), mul2(mRY(p1[1]), mul2(mRY(eb), mH()))));
    M2 A2 = mul2(mRX(p1[10]), mul2(mRY(p1[8]), mRZ(p1[6])));
    M2 B2 = mul2(mRY(p1[11]), mul2(mRZ(p1[9]), mRX(p1[7])));
    M4 G1 = vqc_gate(A1,B1,A2,B2);
    M2 A1b = mul2(mRZ(p2[4]), mul2(mRY(p2[2]), mRX(p2[0])));
    M2 B1b = mul2(mRX(p2[5]), mul2(mRZ(p2[3]), mRY(p2[1])));
    M2 A2b = mul2(mRX(p2[10]), mul2(mRY(p2[8]), mRZ(p2[6])));
    M2 B2b = mul2(mRY(p2[11]), mul2(mRZ(p2[9]), mRX(p2[7])));
    M4 Gm = mul4(vqc_gate(A1b,B1b,A2b,B2b), G1);
    float2* dst = (float2*)wsf + i*16;
    #pragma unroll
    for (int r=0;r<4;r++)
      #pragma unroll
      for (int c=0;c<4;c++) dst[c*4+r]=Gm.m[r*4+c];   // column-major
  } else if (t < 10){
    int i = t-5;
    const float* sa = params + 130 + (2*i)*3;
    const float* sb = params + 130 + (2*i+1)*3;
    M2 Ra = mul2(mRZ(sa[2]), mul2(mRY(sa[1]), mRZ(sa[0])));
    M2 Rb = mul2(mRZ(sb[2]), mul2(mRY(sb[1]), mRZ(sb[0])));
    M4 R = kron(Ra, Rb);
    float2* dst = (float2*)wsf + 80 + i*16;
    #pragma unroll
    for (int r=0;r<4;r++)
      #pragma unroll
      for (int c=0;c<4;c++) dst[c*4+r]=R.m[r*4+c];    // column-major
  } else if (t < 20){
    int c = t-10;                                     // cbias = b_fc + w_fc @ b_in
    float s = b_fc[c];
    #pragma unroll
    for (int q=0;q<10;q++) s += w_fc[c*10+q]*b_in[q];
    wsf[320+c] = s;
  }
}

// ---------- main: one WAVE = one sample; 16 amps/lane; 5 rounds; no barriers ----------
__global__ __launch_bounds__(256,4) void qm_sim(
    const float* __restrict__ x, const float* __restrict__ w_in,
    const float* __restrict__ w_fc, const float* __restrict__ wsf,
    float* __restrict__ out)
{
  __shared__ __align__(16) f2 psi[4096];               // 4 waves x 1024
  const int t = threadIdx.x;
  const int l = t & 63, wid = t >> 6;
  const int sample = (blockIdx.x<<2) + wid;
  char* PB = (char*)(psi + (wid<<10));
  const float* xr = x + ((size_t)sample<<10);
  const f2* G = (const f2*)wsf;                        // gates: uniform -> scalar loads

  // ---- GEMV partials (contiguous m in [16l,16l+16)) + norm ----
  float4 xv0 = *(const float4*)(xr + (l<<4));
  float4 xv1 = *(const float4*)(xr + (l<<4) + 4);
  float4 xv2 = *(const float4*)(xr + (l<<4) + 8);
  float4 xv3 = *(const float4*)(xr + (l<<4) + 12);
  f2 xc[8];
  xc[0]=mk(xv0.x,xv0.y); xc[1]=mk(xv0.z,xv0.w); xc[2]=mk(xv1.x,xv1.y); xc[3]=mk(xv1.z,xv1.w);
  xc[4]=mk(xv2.x,xv2.y); xc[5]=mk(xv2.z,xv2.w); xc[6]=mk(xv3.x,xv3.y); xc[7]=mk(xv3.z,xv3.w);
  f2 xq[5];
  #pragma unroll
  for (int q=0;q<10;q++){
    const float4* wr = (const float4*)(w_in + (q<<10) + (l<<4));
    float4 w0=wr[0], w1=wr[1], w2=wr[2], w3=wr[3];
    f2 a;
    a  = xc[0]*mk(w0.x,w0.y);
    a += xc[1]*mk(w0.z,w0.w);
    a += xc[2]*mk(w1.x,w1.y);
    a += xc[3]*mk(w1.z,w1.w);
    a += xc[4]*mk(w2.x,w2.y);
    a += xc[5]*mk(w2.z,w2.w);
    a += xc[6]*mk(w3.x,w3.y);
    a += xc[7]*mk(w3.z,w3.w);
    float s = a.x + a.y;
    if (q&1) xq[q>>1].y = s; else xq[q>>1].x = s;      // pack pairs for f2 reduce later
  }
  f2 nn = xc[0]*xc[0]; nn += xc[1]*xc[1]; nn += xc[2]*xc[2]; nn += xc[3]*xc[3];
  nn += xc[4]*xc[4]; nn += xc[5]*xc[5]; nn += xc[6]*xc[6]; nn += xc[7]*xc[7];
  float n2 = nn.x + nn.y;
  // strided x loads (issue early; L1/L2 hits)
  float xs[16];
  #pragma unroll
  for (int k=0;k<16;k++) xs[k] = xr[(k<<6)|l];
  #pragma unroll
  for (int o=1;o<64;o<<=1) n2 += __shfl_xor(n2, o);
  float rn = rsqrtf(n2);

  // ===== R1: amps from x (state s = (k<<6)|l ; i=k>>2 bits 9,8 ; j=k&3 bits 7,6) =====
  f2 A[16];
  #pragma unroll
  for (int k=0;k<16;k++) A[k] = mk(xs[k]*rn, 0.f);
  #pragma unroll
  for (int j=0;j<4;j++) quadS(G+ 0, A[j], A[4+j], A[8+j], A[12+j]);     // G98 (i-axis)
  #pragma unroll
  for (int i=0;i<4;i++) quadS(G+16, A[4*i], A[4*i+1], A[4*i+2], A[4*i+3]); // G76 (j-axis)
  const int Lb = (l ^ (l>>4)) << 3;                    // SW((k<<6)|l) = Lb ^ ck
  #pragma unroll
  for (int k=0;k<16;k++){
    const int ck = (((k<<6) ^ ((k&3)<<2)) << 3);
    *(f2*)(PB + (Lb ^ ck)) = A[k];
  }
  WAIT_LDS;

  // ===== R2: free bits {5,4}=i, {3,2}=j ; lane: {9..6}=l>>2, {1,0}=l&3 =====
  const int L2 = ((((l>>2)<<6)) ^ (l&3) ^ (l&0xC)) << 3;
  #pragma unroll
  for (int k=0;k<16;k++){
    const int ck = (((k<<2) ^ (k>>2)) << 3);
    A[k] = *(const f2*)(PB + (L2 ^ ck));
  }
  #pragma unroll
  for (int j=0;j<4;j++) quadS(G+32, A[j], A[4+j], A[8+j], A[12+j]);     // G54
  #pragma unroll
  for (int i=0;i<4;i++) quadS(G+48, A[4*i], A[4*i+1], A[4*i+2], A[4*i+3]); // G32
  #pragma unroll
  for (int k=0;k<16;k++){
    const int ck = (((k<<2) ^ (k>>2)) << 3);
    *(f2*)(PB + (L2 ^ ck)) = A[k];
  }
  WAIT_LDS;

  // ===== R3: G10 (pre-bits 1,0) + ring perm + rot32 (post-bits 3,2) =====
  // u = u0 ^ IOFF[i] ^ j ; u0 = (l<<4)^(l<<3) (even parity vs P rows, bits 1:0 = 0)
  {
    const int L3 = (((l<<4) ^ (l<<3)) ^ ((l ^ (l>>1)) & 15)) << 3;
    const int IOFF[4] = {0, 0x6, 0xC, 0xA};
    #pragma unroll
    for (int k=0;k<16;k++){
      const int ck = ((IOFF[k>>2] ^ (k&3)) << 3);
      A[k] = *(const f2*)(PB + (L3 ^ ck));
    }
    // G10 on j-axis; pre-bits(1,0) = j ^ 2*i0 -> swap args for i in {1,3}
    quadS(G+64, A[0], A[1], A[2], A[3]);
    quadS(G+64, A[6], A[7], A[4], A[5]);
    quadS(G+64, A[8], A[9], A[10], A[11]);
    quadS(G+64, A[14], A[15], A[12], A[13]);
    // rot pair 3 (post-perm bits 3,2) on i-axis; index = i exactly
    #pragma unroll
    for (int j=0;j<4;j++) quadS(G+128, A[j], A[4+j], A[8+j], A[12+j]);
    // write post-perm: v = (l<<4) ^ (i<<2) ^ PJ[j] ; SW(v) = v ^ (l&15)
    const int L3w = ((l<<4) ^ (l&15)) << 3;
    const int PJ[4] = {0, 0x201, 0x203, 0x002};
    #pragma unroll
    for (int k=0;k<16;k++){
      const int ck = (((k & 0xC) ^ PJ[k&3]) << 3);
      *(f2*)(PB + (L3w ^ ck)) = A[k];
    }
  }
  WAIT_LDS;

  // ===== R4: rot98 + rot76 ; standard layout (same formula as R1 write) =====
  #pragma unroll
  for (int k=0;k<16;k++){
    const int ck = (((k<<6) ^ ((k&3)<<2)) << 3);
    A[k] = *(const f2*)(PB + (Lb ^ ck));
  }
  #pragma unroll
  for (int j=0;j<4;j++) quadS(G+80, A[j], A[4+j], A[8+j], A[12+j]);     // rot98
  #pragma unroll
  for (int i=0;i<4;i++) quadS(G+96, A[4*i], A[4*i+1], A[4*i+2], A[4*i+3]); // rot76
  #pragma unroll
  for (int k=0;k<16;k++){
    const int ck = (((k<<6) ^ ((k&3)<<2)) << 3);
    *(f2*)(PB + (Lb ^ ck)) = A[k];
  }
  WAIT_LDS;

  // ===== R5: rot54 (i = bits 5,4) + rot10 (j = bits 1,0) ; lane {9..6,3,2} =====
  const int L5 = ((((l>>2)<<6)) ^ ((l&3)<<2) ^ (l&0xC)) << 3;
  #pragma unroll
  for (int k=0;k<16;k++){
    const int ck = ((((k>>2)<<4) ^ (k>>2) ^ (k&3)) << 3);
    A[k] = *(const f2*)(PB + (L5 ^ ck));
  }
  #pragma unroll
  for (int j=0;j<4;j++) quadS(G+112, A[j], A[4+j], A[8+j], A[12+j]);    // rot54
  #pragma unroll
  for (int i=0;i<4;i++) quadS(G+144, A[4*i], A[4*i+1], A[4*i+2], A[4*i+3]); // rot10

  // probs + scatter at ring#2-permuted index, padded layout idx = tgt + (tgt>>4)
  float p[16];
  #pragma unroll
  for (int k=0;k<16;k++){ f2 s = A[k]*A[k]; p[k] = s.x + s.y; }
  {
    int sl = ((l>>2)<<6) | ((l&3)<<2);
    int sc = sl; sc ^= sc>>1; sc ^= sc>>2; sc ^= sc>>4; sc ^= sc>>8;    // prefix-xor scan
    int Pl = (sc & 0x1FF) | (((sc ^ (sc>>9)) & 1) << 9);                // P(lane-part)
    float* PF = (float*)PB;
    const int PI[4]  = {0, 0x21F, 0x23F, 0x020};                        // P(i-basis bits 4,5)
    const int PJ2[4] = {0, 0x201, 0x203, 0x002};                        // P(j-basis bits 0,1)
    #pragma unroll
    for (int k=0;k<16;k++){
      int tgt = Pl ^ PI[k>>2] ^ PJ2[k&3];
      PF[tgt + (tgt>>4)] = p[k];
    }
  }
  WAIT_LDS;

  // ===== epilogue: read 16 probs (stride-17 pad: conflict-free, imm offsets) =====
  const float* PR = (const float*)PB + 17*l;           // states s = (l<<4)|r
  float q0=PR[0], q1=PR[1], q2=PR[2], q3=PR[3], q4=PR[4], q5=PR[5], q6=PR[6], q7=PR[7];
  float q8=PR[8], q9=PR[9], q10=PR[10], q11=PR[11], q12=PR[12], q13=PR[13], q14=PR[14], q15=PR[15];

  float D[10];
  // reg tree over state bits 3..0
  float s0=q0+q1, s1=q2+q3, s2=q4+q5, s3=q6+q7, s4=q8+q9, s5=q10+q11, s6=q12+q13, s7=q14+q15;
  float d0=q0-q1, d1=q2-q3, d2=q4-q5, d3=q6-q7, d4=q8-q9, d5=q10-q11, d6=q12-q13, d7=q14-q15;
  D[0] = ((d0+d1)+(d2+d3)) + ((d4+d5)+(d6+d7));
  float ss0=s0+s1, ss1=s2+s3, ss2=s4+s5, ss3=s6+s7;
  D[1] = ((s0-s1)+(s2-s3)) + ((s4-s5)+(s6-s7));
  float sss0=ss0+ss1, sss1=ss2+ss3;
  D[2] = (ss0-ss1) + (ss2-ss3);
  D[3] = sss0 - sss1;
  float S_ = sss0 + sss1;
  // shuffle tree over state bits 9..4 (= lane bits 5..0)
  #pragma unroll
  for (int b=0;b<6;b++){
    const int o = 1<<b;
    float Sp = __shfl_xor(S_, o);
    float dd = S_ - Sp;
    D[4+b] = (l & o) ? -dd : dd;
    S_ += Sp;
    #pragma unroll
    for (int j2=0;j2<4+b;j2++) D[j2] += __shfl_xor(D[j2], o);
  }
  // xp wave-reduce (5 packed f2)
  union LL { f2 v; unsigned long long u; };
  #pragma unroll
  for (int k=0;k<5;k++){
    LL z; z.v = xq[k];
    #pragma unroll
    for (int o=1;o<64;o<<=1){ LL w; w.u = __shfl_xor(z.u, o); z.v += w.v; }
    xq[k] = z.v;
  }

  if (l < 10){
    float o = wsf[320+l];                              // b_fc + w_fc@b_in
    const float* wf = w_fc + l*10;
    #pragma unroll
    for (int q=0;q<10;q++){
      float xpq = (q&1) ? xq[q>>1].y : xq[q>>1].x;
      o += wf[q] * (D[9-q] + xpq);
    }
    out[(size_t)sample*10 + l] = o;
  }
}

extern "C" void kernel_launch(void* const* d_in, const int* in_sizes, int n_in,
                              void* d_out, int out_size, void* d_ws, size_t ws_size,
                              hipStream_t stream) {
  const float* x      = (const float*)d_in[0];
  const float* params = (const float*)d_in[1];
  const float* w_in   = (const float*)d_in[2];
  const float* b_in   = (const float*)d_in[3];
  const float* w_fc   = (const float*)d_in[4];
  const float* b_fc   = (const float*)d_in[5];
  float* out = (float*)d_out;

  float* wsf = (float*)d_ws;                        // 320 f gate mats + 10 f cbias

  int batch = in_sizes[0] >> 10;                    // 8192

  qm_setup<<<dim3(1), dim3(64), 0, stream>>>(params, w_fc, b_in, b_fc, wsf);
  qm_sim<<<dim3(batch>>2), dim3(256), 0, stream>>>(x, w_in, w_fc, wsf, out);
}

// Round 5
// 59.334 us; speedup vs baseline: 2.2883x; 1.3983x over previous
//
#include <hip/hip_runtime.h>

typedef __attribute__((ext_vector_type(2))) float f2;

#define WAIT_LDS asm volatile("s_waitcnt lgkmcnt(0)" ::: "memory")

__device__ __forceinline__ f2 mk(float a, float b){ f2 r; r.x=a; r.y=b; return r; }

// ---------- packed complex, gate operand in SGPR pair ----------
__device__ __forceinline__ void cmadS(f2& c, f2 g, f2 b){
  asm("v_pk_fma_f32 %0, %1, %2, %0 op_sel:[0,0,0] op_sel_hi:[0,1,1]\n\t"
      "v_pk_fma_f32 %0, %1, %2, %0 op_sel:[1,1,0] op_sel_hi:[1,0,1] neg_lo:[1,0,0]"
      : "+v"(c) : "s"(g), "v"(b));
}
__device__ __forceinline__ f2 cmulS(f2 g, f2 b){
  f2 d;
  asm("v_pk_mul_f32 %0, %1, %2 op_sel:[0,0] op_sel_hi:[0,1]\n\t"
      "v_pk_fma_f32 %0, %1, %2, %0 op_sel:[1,1,0] op_sel_hi:[1,0,1] neg_lo:[1,0,0]"
      : "=&v"(d) : "s"(g), "v"(b));
  return d;
}
// c_r = sum_c G[c*4+r] * a_c  (G column-major, uniform -> SGPR)
__device__ __forceinline__ void quadS(const f2* __restrict__ G, f2& a0, f2& a1, f2& a2, f2& a3){
  f2 c0,c1,c2,c3;
  c0=cmulS(G[0],a0);  c1=cmulS(G[1],a0);  c2=cmulS(G[2],a0);  c3=cmulS(G[3],a0);
  cmadS(c0,G[4],a1);  cmadS(c1,G[5],a1);  cmadS(c2,G[6],a1);  cmadS(c3,G[7],a1);
  cmadS(c0,G[8],a2);  cmadS(c1,G[9],a2);  cmadS(c2,G[10],a2); cmadS(c3,G[11],a2);
  cmadS(c0,G[12],a3); cmadS(c1,G[13],a3); cmadS(c2,G[14],a3); cmadS(c3,G[15],a3);
  a0=c0; a1=c1; a2=c2; a3=c3;
}

// ---------- scalar complex (setup only) ----------
__device__ __forceinline__ float2 cmul(float2 a, float2 b){
  return make_float2(a.x*b.x - a.y*b.y, a.x*b.y + a.y*b.x);
}
__device__ __forceinline__ float2 cmad(float2 acc, float2 a, float2 b){
  acc.x += a.x*b.x - a.y*b.y; acc.y += a.x*b.y + a.y*b.x; return acc;
}

// ---------- setup v2: data-driven interpreter, tiny code (I$-friendly) ----------
// chains c=0..49: c<40: pair i=c>>3, slot k=c&7 {A1L1,B1L1,A2L1,B2L1,A1L2,B1L2,A2L2,B2L2}
//                 c>=40: rot chain for qubit q=c-40
// gate types: 0=RX 1=RY 2=RZ 3=H
__global__ __launch_bounds__(64) void qm_setup(
    const float* __restrict__ params, const float* __restrict__ w_fc,
    const float* __restrict__ b_in, const float* __restrict__ b_fc,
    float* __restrict__ wsf){
  __shared__ float2 m2[50][4];
  __shared__ float2 h4[10][16];
  const int t = threadIdx.x;

  if (t < 50){
    int typ[5], pix[5], ng;
    if (t < 40){
      int i = t>>3, k = t&7;
      int P1 = 10 + i*12, P2 = 70 + i*12;
      switch(k){
        case 0: ng=5; typ[0]=3;pix[0]=0;     typ[1]=1;pix[1]=2*i;   typ[2]=0;pix[2]=P1+0;
                      typ[3]=1;pix[3]=P1+2;  typ[4]=2;pix[4]=P1+4;  break;
        case 1: ng=5; typ[0]=3;pix[0]=0;     typ[1]=1;pix[1]=2*i+1; typ[2]=1;pix[2]=P1+1;
                      typ[3]=2;pix[3]=P1+3;  typ[4]=0;pix[4]=P1+5;  break;
        case 2: ng=3; typ[0]=2;pix[0]=P1+6;  typ[1]=1;pix[1]=P1+8;  typ[2]=0;pix[2]=P1+10; break;
        case 3: ng=3; typ[0]=0;pix[0]=P1+7;  typ[1]=2;pix[1]=P1+9;  typ[2]=1;pix[2]=P1+11; break;
        case 4: ng=3; typ[0]=0;pix[0]=P2+0;  typ[1]=1;pix[1]=P2+2;  typ[2]=2;pix[2]=P2+4;  break;
        case 5: ng=3; typ[0]=1;pix[0]=P2+1;  typ[1]=2;pix[1]=P2+3;  typ[2]=0;pix[2]=P2+5;  break;
        case 6: ng=3; typ[0]=2;pix[0]=P2+6;  typ[1]=1;pix[1]=P2+8;  typ[2]=0;pix[2]=P2+10; break;
        default:ng=3; typ[0]=0;pix[0]=P2+7;  typ[1]=2;pix[1]=P2+9;  typ[2]=1;pix[2]=P2+11; break;
      }
    } else {
      int S = 130 + (t-40)*3;
      ng=3; typ[0]=2;pix[0]=S+0; typ[1]=1;pix[1]=S+1; typ[2]=2;pix[2]=S+2;
    }
    float2 M[4] = {{1.f,0.f},{0.f,0.f},{0.f,0.f},{1.f,0.f}};
    #pragma clang loop unroll(disable)
    for (int g=0; g<ng; ++g){
      float2 R[4];
      if (typ[g]==3){
        const float r_=0.70710678118654752f;
        R[0]={r_,0.f}; R[1]={r_,0.f}; R[2]={r_,0.f}; R[3]={-r_,0.f};
      } else {
        float th = params[pix[g]]*0.5f;
        float c = cosf(th), s = sinf(th);
        if (typ[g]==0){ R[0]={c,0.f}; R[1]={0.f,-s}; R[2]={0.f,-s}; R[3]={c,0.f}; }
        else if (typ[g]==1){ R[0]={c,0.f}; R[1]={-s,0.f}; R[2]={s,0.f}; R[3]={c,0.f}; }
        else { R[0]={c,-s}; R[1]={0.f,0.f}; R[2]={0.f,0.f}; R[3]={c,s}; }
      }
      float2 T0=cmad(cmul(R[0],M[0]), R[1], M[2]);
      float2 T1=cmad(cmul(R[0],M[1]), R[1], M[3]);
      float2 T2=cmad(cmul(R[2],M[0]), R[3], M[2]);
      float2 T3=cmad(cmul(R[2],M[1]), R[3], M[3]);
      M[0]=T0; M[1]=T1; M[2]=T2; M[3]=T3;
    }
    m2[t][0]=M[0]; m2[t][1]=M[1]; m2[t][2]=M[2]; m2[t][3]=M[3];
  }
  __syncthreads();
  if (t < 10){                                   // vqc half: CNOT*(A2xB2)*CZ*(A1xB1)
    int i = t>>1, L = t&1;
    const float2* A1 = m2[i*8 + L*4 + 0];
    const float2* B1 = m2[i*8 + L*4 + 1];
    const float2* A2 = m2[i*8 + L*4 + 2];
    const float2* B2 = m2[i*8 + L*4 + 3];
    float2 K1[16], K2[16];
    #pragma clang loop unroll(disable)
    for (int r=0;r<4;r++)
      #pragma clang loop unroll(disable)
      for (int c=0;c<4;c++){
        K1[r*4+c] = cmul(A1[(r>>1)*2+(c>>1)], B1[(r&1)*2+(c&1)]);
        K2[r*4+c] = cmul(A2[(r>>1)*2+(c>>1)], B2[(r&1)*2+(c&1)]);
      }
    #pragma clang loop unroll(disable)
    for (int c=0;c<4;c++){ K1[12+c].x=-K1[12+c].x; K1[12+c].y=-K1[12+c].y; }  // CZ
    #pragma clang loop unroll(disable)
    for (int r=0;r<4;r++){
      int rr = (r==1)?3:(r==3)?1:r;                                          // CNOT row swap
      #pragma clang loop unroll(disable)
      for (int c=0;c<4;c++){
        float2 v = cmul(K2[r*4+0], K1[0+c]);
        v = cmad(v, K2[r*4+1], K1[4+c]);
        v = cmad(v, K2[r*4+2], K1[8+c]);
        v = cmad(v, K2[r*4+3], K1[12+c]);
        h4[t][rr*4+c] = v;
      }
    }
  }
  __syncthreads();
  if (t < 5){                                    // G = H_L2 @ H_L1, col-major out
    const float2* Ga = h4[t*2+1];
    const float2* Gb = h4[t*2+0];
    float2* dst = (float2*)wsf + t*16;
    #pragma clang loop unroll(disable)
    for (int r=0;r<4;r++)
      #pragma clang loop unroll(disable)
      for (int c=0;c<4;c++){
        float2 v = cmul(Ga[r*4+0], Gb[0+c]);
        v = cmad(v, Ga[r*4+1], Gb[4+c]);
        v = cmad(v, Ga[r*4+2], Gb[8+c]);
        v = cmad(v, Ga[r*4+3], Gb[12+c]);
        dst[c*4+r] = v;
      }
  } else if (t < 10){                            // rot pair kron, col-major out
    int i = t-5;
    const float2* Ra = m2[40 + 2*i];
    const float2* Rb = m2[40 + 2*i + 1];
    float2* dst = (float2*)wsf + 80 + i*16;
    #pragma clang loop unroll(disable)
    for (int r=0;r<4;r++)
      #pragma clang loop unroll(disable)
      for (int c=0;c<4;c++)
        dst[c*4+r] = cmul(Ra[(r>>1)*2+(c>>1)], Rb[(r&1)*2+(c&1)]);
  } else if (t < 20){                            // cbias = b_fc + w_fc @ b_in
    int c = t-10;
    float s = b_fc[c];
    #pragma clang loop unroll(disable)
    for (int q=0;q<10;q++) s += w_fc[c*10+q]*b_in[q];
    wsf[320+c] = s;
  }
}

// ---------- main: one WAVE = one sample; 16 amps/lane; 5 rounds; no barriers ----------
__global__ __launch_bounds__(256,4) void qm_sim(
    const float* __restrict__ x, const float* __restrict__ w_in,
    const float* __restrict__ w_fc, const float* __restrict__ wsf,
    float* __restrict__ out)
{
  __shared__ __align__(16) f2 psi[4096];               // 4 waves x 1024
  const int t = threadIdx.x;
  const int l = t & 63, wid = t >> 6;
  const int sample = (blockIdx.x<<2) + wid;
  char* PB = (char*)(psi + (wid<<10));
  const float* xr = x + ((size_t)sample<<10);
  const f2* G = (const f2*)wsf;                        // gates: uniform -> scalar loads

  // ---- GEMV partials (contiguous m in [16l,16l+16)) + norm ----
  float4 xv0 = *(const float4*)(xr + (l<<4));
  float4 xv1 = *(const float4*)(xr + (l<<4) + 4);
  float4 xv2 = *(const float4*)(xr + (l<<4) + 8);
  float4 xv3 = *(const float4*)(xr + (l<<4) + 12);
  f2 xc[8];
  xc[0]=mk(xv0.x,xv0.y); xc[1]=mk(xv0.z,xv0.w); xc[2]=mk(xv1.x,xv1.y); xc[3]=mk(xv1.z,xv1.w);
  xc[4]=mk(xv2.x,xv2.y); xc[5]=mk(xv2.z,xv2.w); xc[6]=mk(xv3.x,xv3.y); xc[7]=mk(xv3.z,xv3.w);
  f2 xq[5];
  #pragma unroll
  for (int q=0;q<10;q++){
    const float4* wr = (const float4*)(w_in + (q<<10) + (l<<4));
    float4 w0=wr[0], w1=wr[1], w2=wr[2], w3=wr[3];
    f2 a;
    a  = xc[0]*mk(w0.x,w0.y);
    a += xc[1]*mk(w0.z,w0.w);
    a += xc[2]*mk(w1.x,w1.y);
    a += xc[3]*mk(w1.z,w1.w);
    a += xc[4]*mk(w2.x,w2.y);
    a += xc[5]*mk(w2.z,w2.w);
    a += xc[6]*mk(w3.x,w3.y);
    a += xc[7]*mk(w3.z,w3.w);
    float s = a.x + a.y;
    if (q&1) xq[q>>1].y = s; else xq[q>>1].x = s;      // pack pairs for f2 reduce later
  }
  f2 nn = xc[0]*xc[0]; nn += xc[1]*xc[1]; nn += xc[2]*xc[2]; nn += xc[3]*xc[3];
  nn += xc[4]*xc[4]; nn += xc[5]*xc[5]; nn += xc[6]*xc[6]; nn += xc[7]*xc[7];
  float n2 = nn.x + nn.y;
  // strided x loads (issue early; L1/L2 hits)
  float xs[16];
  #pragma unroll
  for (int k=0;k<16;k++) xs[k] = xr[(k<<6)|l];
  #pragma unroll
  for (int o=1;o<64;o<<=1) n2 += __shfl_xor(n2, o);
  float rn = rsqrtf(n2);

  // ===== R1: amps from x (state s = (k<<6)|l ; i=k>>2 bits 9,8 ; j=k&3 bits 7,6) =====
  f2 A[16];
  #pragma unroll
  for (int k=0;k<16;k++) A[k] = mk(xs[k]*rn, 0.f);
  #pragma unroll
  for (int j=0;j<4;j++) quadS(G+ 0, A[j], A[4+j], A[8+j], A[12+j]);     // G98 (i-axis)
  #pragma unroll
  for (int i=0;i<4;i++) quadS(G+16, A[4*i], A[4*i+1], A[4*i+2], A[4*i+3]); // G76 (j-axis)
  const int Lb = (l ^ (l>>4)) << 3;                    // SW((k<<6)|l) = Lb ^ ck
  #pragma unroll
  for (int k=0;k<16;k++){
    const int ck = (((k<<6) ^ ((k&3)<<2)) << 3);
    *(f2*)(PB + (Lb ^ ck)) = A[k];
  }
  WAIT_LDS;

  // ===== R2: free bits {5,4}=i, {3,2}=j ; lane: {9..6}=l>>2, {1,0}=l&3 =====
  const int L2 = ((((l>>2)<<6)) ^ (l&3) ^ (l&0xC)) << 3;
  #pragma unroll
  for (int k=0;k<16;k++){
    const int ck = (((k<<2) ^ (k>>2)) << 3);
    A[k] = *(const f2*)(PB + (L2 ^ ck));
  }
  #pragma unroll
  for (int j=0;j<4;j++) quadS(G+32, A[j], A[4+j], A[8+j], A[12+j]);     // G54
  #pragma unroll
  for (int i=0;i<4;i++) quadS(G+48, A[4*i], A[4*i+1], A[4*i+2], A[4*i+3]); // G32
  #pragma unroll
  for (int k=0;k<16;k++){
    const int ck = (((k<<2) ^ (k>>2)) << 3);
    *(f2*)(PB + (L2 ^ ck)) = A[k];
  }
  WAIT_LDS;

  // ===== R3: G10 (pre-bits 1,0) + ring perm + rot32 (post-bits 3,2) =====
  {
    const int L3 = (((l<<4) ^ (l<<3)) ^ ((l ^ (l>>1)) & 15)) << 3;
    const int IOFF[4] = {0, 0x6, 0xC, 0xA};
    #pragma unroll
    for (int k=0;k<16;k++){
      const int ck = ((IOFF[k>>2] ^ (k&3)) << 3);
      A[k] = *(const f2*)(PB + (L3 ^ ck));
    }
    // G10 on j-axis; pre-bits(1,0) = j ^ 2*i0 -> swap args for i in {1,3}
    quadS(G+64, A[0], A[1], A[2], A[3]);
    quadS(G+64, A[6], A[7], A[4], A[5]);
    quadS(G+64, A[8], A[9], A[10], A[11]);
    quadS(G+64, A[14], A[15], A[12], A[13]);
    // rot pair 3 (post-perm bits 3,2) on i-axis; index = i exactly
    #pragma unroll
    for (int j=0;j<4;j++) quadS(G+128, A[j], A[4+j], A[8+j], A[12+j]);
    // write post-perm: v = (l<<4) ^ (i<<2) ^ PJ[j] ; SW(v) = v ^ (l&15)
    const int L3w = ((l<<4) ^ (l&15)) << 3;
    const int PJ[4] = {0, 0x201, 0x203, 0x002};
    #pragma unroll
    for (int k=0;k<16;k++){
      const int ck = (((k & 0xC) ^ PJ[k&3]) << 3);
      *(f2*)(PB + (L3w ^ ck)) = A[k];
    }
  }
  WAIT_LDS;

  // ===== R4: rot98 + rot76 ; standard layout (same formula as R1 write) =====
  #pragma unroll
  for (int k=0;k<16;k++){
    const int ck = (((k<<6) ^ ((k&3)<<2)) << 3);
    A[k] = *(const f2*)(PB + (Lb ^ ck));
  }
  #pragma unroll
  for (int j=0;j<4;j++) quadS(G+80, A[j], A[4+j], A[8+j], A[12+j]);     // rot98
  #pragma unroll
  for (int i=0;i<4;i++) quadS(G+96, A[4*i], A[4*i+1], A[4*i+2], A[4*i+3]); // rot76
  #pragma unroll
  for (int k=0;k<16;k++){
    const int ck = (((k<<6) ^ ((k&3)<<2)) << 3);
    *(f2*)(PB + (Lb ^ ck)) = A[k];
  }
  WAIT_LDS;

  // ===== R5: rot54 (i = bits 5,4) + rot10 (j = bits 1,0) ; lane {9..6,3,2} =====
  const int L5 = ((((l>>2)<<6)) ^ ((l&3)<<2) ^ (l&0xC)) << 3;
  #pragma unroll
  for (int k=0;k<16;k++){
    const int ck = ((((k>>2)<<4) ^ (k>>2) ^ (k&3)) << 3);
    A[k] = *(const f2*)(PB + (L5 ^ ck));
  }
  #pragma unroll
  for (int j=0;j<4;j++) quadS(G+112, A[j], A[4+j], A[8+j], A[12+j]);    // rot54
  #pragma unroll
  for (int i=0;i<4;i++) quadS(G+144, A[4*i], A[4*i+1], A[4*i+2], A[4*i+3]); // rot10

  // probs + scatter at ring#2-permuted index, padded layout idx = tgt + (tgt>>4)
  float p[16];
  #pragma unroll
  for (int k=0;k<16;k++){ f2 s = A[k]*A[k]; p[k] = s.x + s.y; }
  {
    int sl = ((l>>2)<<6) | ((l&3)<<2);
    int sc = sl; sc ^= sc>>1; sc ^= sc>>2; sc ^= sc>>4; sc ^= sc>>8;    // prefix-xor scan
    int Pl = (sc & 0x1FF) | (((sc ^ (sc>>9)) & 1) << 9);                // P(lane-part)
    float* PF = (float*)PB;
    const int PI[4]  = {0, 0x21F, 0x23F, 0x020};                        // P(i-basis bits 4,5)
    const int PJ2[4] = {0, 0x201, 0x203, 0x002};                        // P(j-basis bits 0,1)
    #pragma unroll
    for (int k=0;k<16;k++){
      int tgt = Pl ^ PI[k>>2] ^ PJ2[k&3];
      PF[tgt + (tgt>>4)] = p[k];
    }
  }
  WAIT_LDS;

  // ===== epilogue: read 16 probs (stride-17 pad: conflict-free, imm offsets) =====
  const float* PR = (const float*)PB + 17*l;           // states s = (l<<4)|r
  float q0=PR[0], q1=PR[1], q2=PR[2], q3=PR[3], q4=PR[4], q5=PR[5], q6=PR[6], q7=PR[7];
  float q8=PR[8], q9=PR[9], q10=PR[10], q11=PR[11], q12=PR[12], q13=PR[13], q14=PR[14], q15=PR[15];

  float D[10];
  float s0=q0+q1, s1=q2+q3, s2=q4+q5, s3=q6+q7, s4=q8+q9, s5=q10+q11, s6=q12+q13, s7=q14+q15;
  float d0=q0-q1, d1=q2-q3, d2=q4-q5, d3=q6-q7, d4=q8-q9, d5=q10-q11, d6=q12-q13, d7=q14-q15;
  D[0] = ((d0+d1)+(d2+d3)) + ((d4+d5)+(d6+d7));
  float ss0=s0+s1, ss1=s2+s3, ss2=s4+s5, ss3=s6+s7;
  D[1] = ((s0-s1)+(s2-s3)) + ((s4-s5)+(s6-s7));
  float sss0=ss0+ss1, sss1=ss2+ss3;
  D[2] = (ss0-ss1) + (ss2-ss3);
  D[3] = sss0 - sss1;
  float S_ = sss0 + sss1;
  #pragma unroll
  for (int b=0;b<6;b++){
    const int o = 1<<b;
    float Sp = __shfl_xor(S_, o);
    float dd = S_ - Sp;
    D[4+b] = (l & o) ? -dd : dd;
    S_ += Sp;
    #pragma unroll
    for (int j2=0;j2<4+b;j2++) D[j2] += __shfl_xor(D[j2], o);
  }
  union LL { f2 v; unsigned long long u; };
  #pragma unroll
  for (int k=0;k<5;k++){
    LL z; z.v = xq[k];
    #pragma unroll
    for (int o=1;o<64;o<<=1){ LL w; w.u = __shfl_xor(z.u, o); z.v += w.v; }
    xq[k] = z.v;
  }

  if (l < 10){
    float o = wsf[320+l];                              // b_fc + w_fc@b_in
    const float* wf = w_fc + l*10;
    #pragma unroll
    for (int q=0;q<10;q++){
      float xpq = (q&1) ? xq[q>>1].y : xq[q>>1].x;
      o += wf[q] * (D[9-q] + xpq);
    }
    out[(size_t)sample*10 + l] = o;
  }
}

extern "C" void kernel_launch(void* const* d_in, const int* in_sizes, int n_in,
                              void* d_out, int out_size, void* d_ws, size_t ws_size,
                              hipStream_t stream) {
  const float* x      = (const float*)d_in[0];
  const float* params = (const float*)d_in[1];
  const float* w_in   = (const float*)d_in[2];
  const float* b_in   = (const float*)d_in[3];
  const float* w_fc   = (const float*)d_in[4];
  const float* b_fc   = (const float*)d_in[5];
  float* out = (float*)d_out;

  float* wsf = (float*)d_ws;                        // 320 f gate mats + 10 f cbias

  int batch = in_sizes[0] >> 10;                    // 8192

  qm_setup<<<dim3(1), dim3(64), 0, stream>>>(params, w_fc, b_in, b_fc, wsf);
  qm_sim<<<dim3(batch>>2), dim3(256), 0, stream>>>(x, w_in, w_fc, wsf, out);
}